// Round 5
// baseline (639.871 us; speedup 1.0000x reference)
//
#include <hip/hip_runtime.h>
#include <math.h>

typedef unsigned short u16;
typedef _Float16 f16;
typedef __attribute__((ext_vector_type(8))) _Float16 f16x8;
typedef __attribute__((ext_vector_type(4))) float f32x4;

#define N_ROWS 131072
#define HID 128
#define WS_CH 8192                    // u16 per packed (layer,chunk) region: [hi|lo][nt][lane][c]
#define N_WCH 72                      // 2 layers * 36 chunks
#define N_PCH 8                       // 2 halves * 4 k-chunks of protos

// ---------------------------------------------------------------------------
// f16 split-2: v ~= hi + lo with |v - hi - lo| <= 2^-22 |v|  (fp32-grade)
__device__ __forceinline__ void f16_split(float v, f16& hi, f16& lo) {
    f16 h = (f16)v;
    hi = h;
    lo = (f16)(v - (float)h);
}

// cardinal cubic B-spline on uniform knots g[j] = (j-3)*0.4 - 1 -> 8 coef slots
__device__ __forceinline__ void spline8(float xv, float* a8) {
    float s  = (xv + 2.2f) * 2.5f;
    float tf = floorf(s);
    int   tt = (int)tf;
    bool valid = (tt >= 0) && (tt <= 10);
    float kt = (float)(tt - 3) * 0.4f - 1.0f;
    float u  = (xv - kt) * 2.5f;
    float u2 = u * u, u3 = u2 * u;
    float om = 1.0f - u;
    float b3 = u3 * (1.0f / 6.0f);                                   // slot tt
    float b2 = (-3.f * u3 + 3.f * u2 + 3.f * u + 1.f) * (1.0f / 6.0f); // tt-1
    float b1 = (3.f * u3 - 6.f * u2 + 4.f) * (1.0f / 6.0f);          // tt-2
    float b0 = om * om * om * (1.0f / 6.0f);                         // tt-3
    #pragma unroll
    for (int c = 0; c < 8; ++c) {
        int d = tt - c;
        float v = 0.f;
        v = (d == 0) ? b3 : v;
        v = (d == 1) ? b2 : v;
        v = (d == 2) ? b1 : v;
        v = (d == 3) ? b0 : v;
        a8[c] = valid ? v : 0.f;
    }
}

// ---------------------------------------------------------------------------
// Pre-pack: weights (spline_w*scaler folded) and protos -> f16 hi/lo in MFMA
// B-fragment order. ws region r (u16 stride WS_CH):
//   r = l*36 + ch           : layer weights, B[k_local][o]
//   r = 72 + half*4 + kc    : protos,       B[k_local][p_local]
// in-region: idx = (nt*64 + lane)*8 + c ; hi at +0, lo at +4096.
// ---------------------------------------------------------------------------
__global__ __launch_bounds__(256)
void pack_weights(const float* __restrict__ bw1, const float* __restrict__ sw1,
                  const float* __restrict__ sc1,
                  const float* __restrict__ bw2, const float* __restrict__ sw2,
                  const float* __restrict__ sc2,
                  const float* __restrict__ protos, u16* __restrict__ ws)
{
    int gid = blockIdx.x * 256 + threadIdx.x;
    if (gid < N_WCH * 4096) {
        int l  = gid / (36 * 4096);
        int r  = gid % (36 * 4096);
        int ch = r / 4096;
        int e  = r % 4096;             // o*32 + k_local
        int o  = e >> 5;
        int kl = e & 31;
        const float* bw = l ? bw2 : bw1;
        const float* sw = l ? sw2 : sw1;
        const float* sc = l ? sc2 : sc1;
        float v;
        if (ch < 4) {
            v = bw[o * HID + ch * 32 + kl];
        } else {
            int i = (ch - 4) * 4 + (kl >> 3);
            v = sw[(o * HID + i) * 8 + (kl & 7)] * sc[o * HID + i];
        }
        f16 hi, lo; f16_split(v, hi, lo);
        int nt = o >> 4, n = o & 15, kq = kl >> 3, c = kl & 7;
        size_t base = (size_t)(l * 36 + ch) * WS_CH;
        size_t idx  = ((size_t)nt * 64 + kq * 16 + n) * 8 + c;
        ws[base + idx]        = __builtin_bit_cast(u16, hi);
        ws[base + 4096 + idx] = __builtin_bit_cast(u16, lo);
    } else if (gid < (N_WCH + N_PCH) * 4096) {
        int r  = gid - N_WCH * 4096;
        int hk = r / 4096;             // half*4 + kc
        int e  = r % 4096;             // p_local*32 + kl
        int pl = e >> 5;
        int kl = e & 31;
        int half = hk >> 2, kc = hk & 3;
        float v = protos[(size_t)(half * 128 + pl) * HID + kc * 32 + kl];
        f16 hi, lo; f16_split(v, hi, lo);
        int nt = pl >> 4, n = pl & 15, kq = kl >> 3, c = kl & 7;
        size_t base = (size_t)(N_WCH + hk) * WS_CH;
        size_t idx  = ((size_t)nt * 64 + kq * 16 + n) * 8 + c;
        ws[base + idx]        = __builtin_bit_cast(u16, hi);
        ws[base + 4096 + idx] = __builtin_bit_cast(u16, lo);
    }
}

// ---------------------------------------------------------------------------
// Fused main kernel, barrier-free K-loop:
//   - every LDS row of t is written AND read only by its owning wave
//     (x-stage, A-build, C-writeback, emb epilogue, argmax all wave-local)
//   - B fragments load straight from global (L2-resident wpack) into VGPRs;
//     compiler-managed vmcnt, no global_load_lds, no Bfrag LDS, no barriers
//   - single __syncthreads() for the cross-wave rnp table
// ---------------------------------------------------------------------------
__global__ __launch_bounds__(256, 2)
void kan_fused(const float* __restrict__ x, const float* __restrict__ protos,
               const u16* __restrict__ wpack,
               float* __restrict__ emb_out, float* __restrict__ assign_out)
{
    __shared__ float t[64][132];          // x -> h -> emb tile (wave-local rows)
    __shared__ float rnp[256];

    const int tid  = threadIdx.x;
    const int lane = tid & 63;
    const int w    = tid >> 6;            // wave 0..3
    const int m    = lane & 15;           // A-row / B-col within 16-tile
    const int q    = lane >> 4;           // 0..3
    const int row  = w * 16 + m;          // this lane's A row (own wave's rows)
    const int brow = blockIdx.x * 64;

    // ---- proto inverse norms (one proto per thread; cross-wave table) ----
    {
        const float4* pr = (const float4*)(protos + (size_t)tid * HID);
        float s = 0.0f;
        #pragma unroll
        for (int j = 0; j < 32; ++j) {
            float4 v = pr[j];
            s += v.x * v.x + v.y * v.y + v.z * v.z + v.w * v.w;
        }
        rnp[tid] = 1.0f / fmaxf(sqrtf(s), 1e-8f);
    }

    // ---- stage x tile, wave-local rows ----
    {
        const int rl = w * 16 + (lane >> 2);
        const int kq2 = lane & 3;
        const float4* src = (const float4*)(x + (size_t)(brow + rl) * HID + kq2 * 32);
        #pragma unroll
        for (int j = 0; j < 8; ++j) {
            float4 v = src[j];
            int k = kq2 * 32 + j * 4;
            t[rl][k] = v.x; t[rl][k + 1] = v.y; t[rl][k + 2] = v.z; t[rl][k + 3] = v.w;
        }
    }
    __syncthreads();   // the ONLY barrier: publishes rnp (and x-tile, defensively)

    union { f16x8 v; f16 h[8]; } ah, al;
    f32x4 acc[8];

    // ================= two KAN layers (no barriers) =================
    for (int l = 0; l < 2; ++l) {
        #pragma unroll
        for (int nt = 0; nt < 8; ++nt) acc[nt] = (f32x4){0.f, 0.f, 0.f, 0.f};

        for (int ch = 0; ch < 36; ++ch) {
            // ---- A fragment in registers (reads own-wave t rows only) ----
            float a8[8];
            if (ch < 4) {
                float4 xv0 = *(const float4*)&t[row][ch * 32 + q * 8];
                float4 xv1 = *(const float4*)&t[row][ch * 32 + q * 8 + 4];
                float xs[8] = { xv0.x, xv0.y, xv0.z, xv0.w, xv1.x, xv1.y, xv1.z, xv1.w };
                #pragma unroll
                for (int j = 0; j < 8; ++j)
                    a8[j] = xs[j] / (1.0f + __expf(-xs[j]));   // silu
            } else {
                spline8(t[row][(ch - 4) * 4 + q], a8);         // feature i0+q
            }
            #pragma unroll
            for (int j = 0; j < 8; ++j) f16_split(a8[j], ah.h[j], al.h[j]);

            // ---- B fragments straight from global (L2) into VGPRs ----
            const u16* cb = wpack + (size_t)(l * 36 + ch) * WS_CH + (size_t)lane * 8;
            #pragma unroll
            for (int nt = 0; nt < 8; ++nt) {
                f16x8 bh = *(const f16x8*)(cb + nt * 512);
                f16x8 bl = *(const f16x8*)(cb + 4096 + nt * 512);
                acc[nt] = __builtin_amdgcn_mfma_f32_16x16x32_f16(ah.v, bh, acc[nt], 0, 0, 0);
                acc[nt] = __builtin_amdgcn_mfma_f32_16x16x32_f16(ah.v, bl, acc[nt], 0, 0, 0);
                acc[nt] = __builtin_amdgcn_mfma_f32_16x16x32_f16(al.v, bh, acc[nt], 0, 0, 0);
                acc[nt] = __builtin_amdgcn_mfma_f32_16x16x32_f16(al.v, bl, acc[nt], 0, 0, 0);
            }
        }

        // ---- C/D -> t (col = lane&15, row = q*4 + reg); own-wave rows only.
        // Intra-wave ordering (lockstep + in-order LDS pipe) makes this safe
        // without a barrier: all lanes' ch=35 reads precede these writes.
        #pragma unroll
        for (int nt = 0; nt < 8; ++nt)
            #pragma unroll
            for (int r = 0; r < 4; ++r)
                t[w * 16 + q * 4 + r][nt * 16 + m] = acc[nt][r];
    }

    // ---- emb epilogue: wave-local rows, float4 stores ----
    {
        const int rl = w * 16 + (lane >> 2);
        const int kq2 = lane & 3;
        float* dst = emb_out + (size_t)(brow + rl) * HID + kq2 * 32;
        #pragma unroll
        for (int j = 0; j < 8; ++j)
            *(float4*)(dst + j * 4) = *(const float4*)&t[rl][kq2 * 32 + j * 4];
    }

    // ================= cosine-sim argmax (no barriers) =================
    // row-norm is a positive per-row scale -> argmax-invariant; apply rnp only.
    float best[4]; int bi[4];
    #pragma unroll
    for (int r = 0; r < 4; ++r) { best[r] = -3.402823466e+38f; bi[r] = 0; }

    for (int half = 0; half < 2; ++half) {
        #pragma unroll
        for (int nt = 0; nt < 8; ++nt) acc[nt] = (f32x4){0.f, 0.f, 0.f, 0.f};

        for (int kc = 0; kc < 4; ++kc) {
            float4 ev0 = *(const float4*)&t[row][kc * 32 + q * 8];
            float4 ev1 = *(const float4*)&t[row][kc * 32 + q * 8 + 4];
            float es[8] = { ev0.x, ev0.y, ev0.z, ev0.w, ev1.x, ev1.y, ev1.z, ev1.w };
            #pragma unroll
            for (int j = 0; j < 8; ++j) f16_split(es[j], ah.h[j], al.h[j]);

            const u16* cb = wpack + (size_t)(N_WCH + half * 4 + kc) * WS_CH
                          + (size_t)lane * 8;
            #pragma unroll
            for (int nt = 0; nt < 8; ++nt) {
                f16x8 bh = *(const f16x8*)(cb + nt * 512);
                f16x8 bl = *(const f16x8*)(cb + 4096 + nt * 512);
                acc[nt] = __builtin_amdgcn_mfma_f32_16x16x32_f16(ah.v, bh, acc[nt], 0, 0, 0);
                acc[nt] = __builtin_amdgcn_mfma_f32_16x16x32_f16(ah.v, bl, acc[nt], 0, 0, 0);
                acc[nt] = __builtin_amdgcn_mfma_f32_16x16x32_f16(al.v, bh, acc[nt], 0, 0, 0);
                acc[nt] = __builtin_amdgcn_mfma_f32_16x16x32_f16(al.v, bl, acc[nt], 0, 0, 0);
            }
        }

        // ascending p within lane + strict '>' keeps FIRST max (np.argmax)
        #pragma unroll
        for (int nt = 0; nt < 8; ++nt) {
            int p = half * 128 + nt * 16 + m;
            float rp = rnp[p];
            #pragma unroll
            for (int r = 0; r < 4; ++r) {
                float v = acc[nt][r] * rp;
                if (v > best[r]) { best[r] = v; bi[r] = p; }
            }
        }
    }

    // reduce over the 16 lanes (cols) sharing each row; tie -> smaller index
    #pragma unroll
    for (int r = 0; r < 4; ++r) {
        #pragma unroll
        for (int off = 1; off < 16; off <<= 1) {
            float ov = __shfl_xor(best[r], off);
            int   oi = __shfl_xor(bi[r], off);
            if (ov > best[r] || (ov == best[r] && oi < bi[r])) { best[r] = ov; bi[r] = oi; }
        }
        if (m == 0)
            assign_out[(size_t)brow + w * 16 + q * 4 + r] = (float)bi[r];
    }
}

// ---------------------------------------------------------------------------
extern "C" void kernel_launch(void* const* d_in, const int* in_sizes, int n_in,
                              void* d_out, int out_size, void* d_ws, size_t ws_size,
                              hipStream_t stream) {
    (void)in_sizes; (void)n_in; (void)out_size; (void)ws_size;

    const float* x      = (const float*)d_in[0];
    const float* protos = (const float*)d_in[1];
    // d_in[2] = grid: uniform knots (j-3)*0.4 - 1, hardcoded
    const float* bw1 = (const float*)d_in[3];
    const float* sw1 = (const float*)d_in[4];
    const float* sc1 = (const float*)d_in[5];
    const float* bw2 = (const float*)d_in[6];
    const float* sw2 = (const float*)d_in[7];
    const float* sc2 = (const float*)d_in[8];

    float* out    = (float*)d_out;
    float* embp   = out;                             // (N,128)
    float* assign = out + (size_t)N_ROWS * HID;      // (N,) as float
    u16*   wpack  = (u16*)d_ws;                      // 1.31 MB packed fragments

    pack_weights<<<dim3((N_WCH + N_PCH) * 4096 / 256), dim3(256), 0, stream>>>(
        bw1, sw1, sc1, bw2, sw2, sc2, protos, wpack);
    kan_fused<<<dim3(N_ROWS / 64), dim3(256), 0, stream>>>(
        x, protos, wpack, embp, assign);
}

// Round 6
// 469.567 us; speedup vs baseline: 1.3627x; 1.3627x over previous
//
#include <hip/hip_runtime.h>
#include <math.h>

typedef unsigned short u16;
typedef _Float16 f16;
typedef __attribute__((ext_vector_type(8))) _Float16 f16x8;
typedef __attribute__((ext_vector_type(4))) float f32x4;

#define N_ROWS 131072
#define HID 128
#define WS_CH 8192                    // u16 per packed region: [hi|lo][nt][lane][c]
#define N_WCH 72                      // 2 layers * 36 chunks
#define N_REG 80                      // + 8 proto regions (contiguous pipeline)

// ---------------------------------------------------------------------------
// f16 split-2: v ~= hi + lo with |v - hi - lo| <= 2^-22 |v|  (fp32-grade)
__device__ __forceinline__ void f16_split(float v, f16& hi, f16& lo) {
    f16 h = (f16)v;
    hi = h;
    lo = (f16)(v - (float)h);
}

// cardinal cubic B-spline on uniform knots g[j] = (j-3)*0.4 - 1 -> 8 coef slots
__device__ __forceinline__ void spline8(float xv, float* a8) {
    float s  = (xv + 2.2f) * 2.5f;
    float tf = floorf(s);
    int   tt = (int)tf;
    bool valid = (tt >= 0) && (tt <= 10);
    float kt = (float)(tt - 3) * 0.4f - 1.0f;
    float u  = (xv - kt) * 2.5f;
    float u2 = u * u, u3 = u2 * u;
    float om = 1.0f - u;
    float b3 = u3 * (1.0f / 6.0f);                                     // slot tt
    float b2 = (-3.f * u3 + 3.f * u2 + 3.f * u + 1.f) * (1.0f / 6.0f); // tt-1
    float b1 = (3.f * u3 - 6.f * u2 + 4.f) * (1.0f / 6.0f);            // tt-2
    float b0 = om * om * om * (1.0f / 6.0f);                           // tt-3
    #pragma unroll
    for (int c = 0; c < 8; ++c) {
        int d = tt - c;
        float v = 0.f;
        v = (d == 0) ? b3 : v;
        v = (d == 1) ? b2 : v;
        v = (d == 2) ? b1 : v;
        v = (d == 3) ? b0 : v;
        a8[c] = valid ? v : 0.f;
    }
}

#define GLOAD_LDS16(g, l)                                                         \
    __builtin_amdgcn_global_load_lds(                                             \
        (const __attribute__((address_space(1))) unsigned int*)(g),               \
        (__attribute__((address_space(3))) unsigned int*)(l), 16, 0, 0)

// ---------------------------------------------------------------------------
// Pre-pack: weights (spline_w*scaler folded) and protos -> f16 hi/lo in MFMA
// B-fragment order. ws region r (u16 stride WS_CH):
//   r = l*36 + ch           : layer weights, B[k_local][o]
//   r = 72 + half*4 + kc    : protos,       B[k_local][p_local]
// in-region: idx = (nt*64 + kq*16 + n)*8 + c ; hi at +0, lo at +4096.
// ---------------------------------------------------------------------------
__global__ __launch_bounds__(256)
void pack_weights(const float* __restrict__ bw1, const float* __restrict__ sw1,
                  const float* __restrict__ sc1,
                  const float* __restrict__ bw2, const float* __restrict__ sw2,
                  const float* __restrict__ sc2,
                  const float* __restrict__ protos, u16* __restrict__ ws)
{
    int gid = blockIdx.x * 256 + threadIdx.x;
    if (gid < N_WCH * 4096) {
        int l  = gid / (36 * 4096);
        int r  = gid % (36 * 4096);
        int ch = r / 4096;
        int e  = r % 4096;             // o*32 + k_local
        int o  = e >> 5;
        int kl = e & 31;
        const float* bw = l ? bw2 : bw1;
        const float* sw = l ? sw2 : sw1;
        const float* sc = l ? sc2 : sc1;
        float v;
        if (ch < 4) {
            v = bw[o * HID + ch * 32 + kl];
        } else {
            int i = (ch - 4) * 4 + (kl >> 3);
            v = sw[(o * HID + i) * 8 + (kl & 7)] * sc[o * HID + i];
        }
        f16 hi, lo; f16_split(v, hi, lo);
        int nt = o >> 4, n = o & 15, kq = kl >> 3, c = kl & 7;
        size_t base = (size_t)(l * 36 + ch) * WS_CH;
        size_t idx  = ((size_t)nt * 64 + kq * 16 + n) * 8 + c;
        ws[base + idx]        = __builtin_bit_cast(u16, hi);
        ws[base + 4096 + idx] = __builtin_bit_cast(u16, lo);
    } else if (gid < N_REG * 4096) {
        int r  = gid - N_WCH * 4096;
        int hk = r / 4096;             // half*4 + kc
        int e  = r % 4096;             // p_local*32 + kl
        int pl = e >> 5;
        int kl = e & 31;
        int half = hk >> 2, kc = hk & 3;
        float v = protos[(size_t)(half * 128 + pl) * HID + kc * 32 + kl];
        f16 hi, lo; f16_split(v, hi, lo);
        int nt = pl >> 4, n = pl & 15, kq = kl >> 3, c = kl & 7;
        size_t base = (size_t)(N_WCH + hk) * WS_CH;
        size_t idx  = ((size_t)nt * 64 + kq * 16 + n) * 8 + c;
        ws[base + idx]        = __builtin_bit_cast(u16, hi);
        ws[base + 4096 + idx] = __builtin_bit_cast(u16, lo);
    }
}

// ---------------------------------------------------------------------------
// Fused main kernel with pipelined B staging:
//   per chunk g: __syncthreads() [drains prefetch issued one iteration ago]
//   -> issue global_load_lds for g+1 into other buffer -> A-build (VALU)
//   -> MFMA on buffer g&1. Regions 0..79 form one continuous pipeline.
// All t-tile accesses are wave-local rows (no extra barriers needed).
// f16 split hi/lo, 3 MFMA products (al*bl dropped: error ~3*2^-22, fp32-grade).
// ---------------------------------------------------------------------------
__global__ __launch_bounds__(256, 2)
void kan_fused(const float* __restrict__ x, const float* __restrict__ protos,
               const u16* __restrict__ wpack,
               float* __restrict__ emb_out, float* __restrict__ assign_out)
{
    __shared__ float t[64][132];             // x -> h -> emb tile (wave-local rows)
    __shared__ u16   Bbuf[2][2][8][64][8];   // [slot][hi/lo][nt][lane][c]
    __shared__ float rnp[256];

    const int tid  = threadIdx.x;
    const int lane = tid & 63;
    const int w    = tid >> 6;               // wave 0..3
    const int m    = lane & 15;              // A-row / B-col within 16-tile
    const int q    = lane >> 4;              // 0..3
    const int row  = w * 16 + m;             // this lane's A row (own wave's rows)
    const int brow = blockIdx.x * 64;

    // per-wave staging pointers (wave w stages bytes [w*4096, w*4096+4096))
    const char* gbase = (const char*)wpack + (size_t)w * 4096 + (size_t)lane * 16;
    char*       lbase = (char*)&Bbuf[0][0][0][0][0] + w * 4096;

    // ---- prefetch region 0 into slot 0 (completes at first barrier) ----
    #pragma unroll
    for (int i = 0; i < 4; ++i)
        GLOAD_LDS16(gbase + i * 1024, lbase + i * 1024);

    // ---- proto inverse norms (one proto per thread; cross-wave table) ----
    {
        const float4* pr = (const float4*)(protos + (size_t)tid * HID);
        float s = 0.0f;
        #pragma unroll
        for (int j = 0; j < 32; ++j) {
            float4 v = pr[j];
            s += v.x * v.x + v.y * v.y + v.z * v.z + v.w * v.w;
        }
        rnp[tid] = 1.0f / fmaxf(sqrtf(s), 1e-8f);
    }

    // ---- stage x tile, wave-local rows ----
    {
        const int rl = w * 16 + (lane >> 2);
        const int kq2 = lane & 3;
        const float4* src = (const float4*)(x + (size_t)(brow + rl) * HID + kq2 * 32);
        #pragma unroll
        for (int j = 0; j < 8; ++j) {
            float4 v = src[j];
            int k = kq2 * 32 + j * 4;
            t[rl][k] = v.x; t[rl][k + 1] = v.y; t[rl][k + 2] = v.z; t[rl][k + 3] = v.w;
        }
    }

    union { f16x8 v; f16 h[8]; } ah, al;
    f32x4 acc[8];

    // ================= two KAN layers =================
    for (int l = 0; l < 2; ++l) {
        #pragma unroll
        for (int nt = 0; nt < 8; ++nt) acc[nt] = (f32x4){0.f, 0.f, 0.f, 0.f};

        for (int ch = 0; ch < 36; ++ch) {
            const int g = l * 36 + ch;
            // drains the prefetch issued one iteration ago -> slot g&1 ready;
            // also protects WAR on slot (g+1)&1 (prev MFMA reads complete).
            __syncthreads();
            if (g + 1 < N_REG) {
                const char* gs = gbase + (size_t)(g + 1) * 16384;
                char*       ls = lbase + ((g + 1) & 1) * 16384;
                #pragma unroll
                for (int i = 0; i < 4; ++i)
                    GLOAD_LDS16(gs + i * 1024, ls + i * 1024);
            }

            // ---- A fragment in registers (own-wave t rows only) ----
            float a8[8];
            if (ch < 4) {
                float4 xv0 = *(const float4*)&t[row][ch * 32 + q * 8];
                float4 xv1 = *(const float4*)&t[row][ch * 32 + q * 8 + 4];
                float xs[8] = { xv0.x, xv0.y, xv0.z, xv0.w, xv1.x, xv1.y, xv1.z, xv1.w };
                #pragma unroll
                for (int j = 0; j < 8; ++j)    // silu via 1-ulp rcp
                    a8[j] = xs[j] * __builtin_amdgcn_rcpf(1.0f + __expf(-xs[j]));
            } else {
                spline8(t[row][(ch - 4) * 4 + q], a8);   // feature i0+q
            }
            #pragma unroll
            for (int j = 0; j < 8; ++j) f16_split(a8[j], ah.h[j], al.h[j]);

            // ---- MFMAs: 8 col-tiles x 3 split products, from slot g&1 ----
            const int cur = g & 1;
            #pragma unroll
            for (int nt = 0; nt < 8; ++nt) {
                f16x8 bh = *(const f16x8*)&Bbuf[cur][0][nt][lane][0];
                f16x8 bl = *(const f16x8*)&Bbuf[cur][1][nt][lane][0];
                acc[nt] = __builtin_amdgcn_mfma_f32_16x16x32_f16(ah.v, bh, acc[nt], 0, 0, 0);
                acc[nt] = __builtin_amdgcn_mfma_f32_16x16x32_f16(ah.v, bl, acc[nt], 0, 0, 0);
                acc[nt] = __builtin_amdgcn_mfma_f32_16x16x32_f16(al.v, bh, acc[nt], 0, 0, 0);
            }
        }

        // ---- C/D -> t (col = lane&15, row = q*4 + reg); own-wave rows only.
        // Same-wave LDS ordering makes this safe without a barrier.
        #pragma unroll
        for (int nt = 0; nt < 8; ++nt)
            #pragma unroll
            for (int r = 0; r < 4; ++r)
                t[w * 16 + q * 4 + r][nt * 16 + m] = acc[nt][r];
    }

    // ---- emb epilogue: wave-local rows, float4 stores ----
    {
        const int rl = w * 16 + (lane >> 2);
        const int kq2 = lane & 3;
        float* dst = emb_out + (size_t)(brow + rl) * HID + kq2 * 32;
        #pragma unroll
        for (int j = 0; j < 8; ++j)
            *(float4*)(dst + j * 4) = *(const float4*)&t[rl][kq2 * 32 + j * 4];
    }

    // ================= cosine-sim argmax =================
    // row-norm is a positive per-row scale -> argmax-invariant; apply rnp only.
    float best[4]; int bi[4];
    #pragma unroll
    for (int r = 0; r < 4; ++r) { best[r] = -3.402823466e+38f; bi[r] = 0; }

    for (int half = 0; half < 2; ++half) {
        #pragma unroll
        for (int nt = 0; nt < 8; ++nt) acc[nt] = (f32x4){0.f, 0.f, 0.f, 0.f};

        for (int kc = 0; kc < 4; ++kc) {
            const int g = N_WCH + half * 4 + kc;
            __syncthreads();
            if (g + 1 < N_REG) {
                const char* gs = gbase + (size_t)(g + 1) * 16384;
                char*       ls = lbase + ((g + 1) & 1) * 16384;
                #pragma unroll
                for (int i = 0; i < 4; ++i)
                    GLOAD_LDS16(gs + i * 1024, ls + i * 1024);
            }

            float4 ev0 = *(const float4*)&t[row][kc * 32 + q * 8];
            float4 ev1 = *(const float4*)&t[row][kc * 32 + q * 8 + 4];
            float es[8] = { ev0.x, ev0.y, ev0.z, ev0.w, ev1.x, ev1.y, ev1.z, ev1.w };
            #pragma unroll
            for (int j = 0; j < 8; ++j) f16_split(es[j], ah.h[j], al.h[j]);

            const int cur = g & 1;
            #pragma unroll
            for (int nt = 0; nt < 8; ++nt) {
                f16x8 bh = *(const f16x8*)&Bbuf[cur][0][nt][lane][0];
                f16x8 bl = *(const f16x8*)&Bbuf[cur][1][nt][lane][0];
                acc[nt] = __builtin_amdgcn_mfma_f32_16x16x32_f16(ah.v, bh, acc[nt], 0, 0, 0);
                acc[nt] = __builtin_amdgcn_mfma_f32_16x16x32_f16(ah.v, bl, acc[nt], 0, 0, 0);
                acc[nt] = __builtin_amdgcn_mfma_f32_16x16x32_f16(al.v, bh, acc[nt], 0, 0, 0);
            }
        }

        // ascending p within lane + strict '>' keeps FIRST max (np.argmax)
        #pragma unroll
        for (int nt = 0; nt < 8; ++nt) {
            int p = half * 128 + nt * 16 + m;
            float rp = rnp[p];
            #pragma unroll
            for (int r = 0; r < 4; ++r) {
                float v = acc[nt][r] * rp;
                if (v > best[r]) { best[r] = v; bi[r] = p; }
            }
        }
    }

    // reduce over the 16 lanes (cols) sharing each row; tie -> smaller index
    #pragma unroll
    for (int r = 0; r < 4; ++r) {
        #pragma unroll
        for (int off = 1; off < 16; off <<= 1) {
            float ov = __shfl_xor(best[r], off);
            int   oi = __shfl_xor(bi[r], off);
            if (ov > best[r] || (ov == best[r] && oi < bi[r])) { best[r] = ov; bi[r] = oi; }
        }
        if (m == 0)
            assign_out[(size_t)brow + w * 16 + q * 4 + r] = (float)bi[r];
    }
}

// ---------------------------------------------------------------------------
extern "C" void kernel_launch(void* const* d_in, const int* in_sizes, int n_in,
                              void* d_out, int out_size, void* d_ws, size_t ws_size,
                              hipStream_t stream) {
    (void)in_sizes; (void)n_in; (void)out_size; (void)ws_size;

    const float* x      = (const float*)d_in[0];
    const float* protos = (const float*)d_in[1];
    // d_in[2] = grid: uniform knots (j-3)*0.4 - 1, hardcoded
    const float* bw1 = (const float*)d_in[3];
    const float* sw1 = (const float*)d_in[4];
    const float* sc1 = (const float*)d_in[5];
    const float* bw2 = (const float*)d_in[6];
    const float* sw2 = (const float*)d_in[7];
    const float* sc2 = (const float*)d_in[8];

    float* out    = (float*)d_out;
    float* embp   = out;                             // (N,128)
    float* assign = out + (size_t)N_ROWS * HID;      // (N,) as float
    u16*   wpack  = (u16*)d_ws;                      // 1.31 MB packed fragments

    pack_weights<<<dim3(N_REG * 4096 / 256), dim3(256), 0, stream>>>(
        bw1, sw1, sc1, bw2, sw2, sc2, protos, wpack);
    kan_fused<<<dim3(N_ROWS / 64), dim3(256), 0, stream>>>(
        x, protos, wpack, embp, assign);
}